// Round 1
// baseline (1045.200 us; speedup 1.0000x reference)
//
#include <hip/hip_runtime.h>
#include <stdint.h>

#define BLK 256

constexpr int Bsz = 8, Ccls = 19, Hh = 512, Ww = 1024;
constexpr int Npix = Hh * Ww;          // 2^19
constexpr int TotPix = Bsz * Npix;     // 2^22
constexpr int NGroup = Bsz * Ccls;     // 152
constexpr int BINS = 4096;

// ---------------------------------------------------------------------------
// K1: per-pixel max/argmax over classes + softmax denominator.
// max_prob = 1/sum(exp(x_c - x_max));  nll later = -log(max_prob).
// ---------------------------------------------------------------------------
__global__ __launch_bounds__(BLK) void k_pixel(const float* __restrict__ pred,
                                               float* __restrict__ mp_out,
                                               uint8_t* __restrict__ lab_out) {
  int p = blockIdx.x * BLK + threadIdx.x;
  int b = p >> 19;                 // / Npix
  int n = p & (Npix - 1);
  const float* base = pred + (size_t)b * Ccls * Npix + n;
  float v[Ccls];
#pragma unroll
  for (int c = 0; c < Ccls; ++c) v[c] = base[(size_t)c * Npix];
  float m = v[0]; int lc = 0;
#pragma unroll
  for (int c = 1; c < Ccls; ++c) {
    if (v[c] > m) { m = v[c]; lc = c; }   // first-max tie-break like argmax
  }
  float s = 0.f;
#pragma unroll
  for (int c = 0; c < Ccls; ++c) s += __expf(v[c] - m);
  mp_out[p] = 1.0f / s;
  lab_out[p] = (uint8_t)lc;
}

// ---------------------------------------------------------------------------
// K2: 12-bit histogram of float bits per (image,class) group.
// ---------------------------------------------------------------------------
__global__ __launch_bounds__(BLK) void k_hist1(const float* __restrict__ mp,
                                               const uint8_t* __restrict__ lab,
                                               uint32_t* __restrict__ hist1) {
  int p = blockIdx.x * BLK + threadIdx.x;
  int b = p >> 19;
  uint32_t u = __float_as_uint(mp[p]);     // positive floats: bits monotone
  int g = b * Ccls + (int)lab[p];
  atomicAdd(&hist1[g * BINS + (int)(u >> 20)], 1u);
}

// ---------------------------------------------------------------------------
// K3: per-group descending scan. Finds bin containing the k-th largest,
// k = int(count * 0.66f) (count derived from histogram total).
// One block per group; thread t owns 16 bins in descending order.
// ---------------------------------------------------------------------------
__global__ __launch_bounds__(BLK) void k_select1(const uint32_t* __restrict__ hist1,
                                                 int* __restrict__ selhi,
                                                 int* __restrict__ rem) {
  int g = blockIdx.x;
  int t = threadIdx.x;
  const uint32_t* h = hist1 + g * BINS;
  uint32_t loc[16]; uint32_t psum = 0;
  int hi = BINS - 1 - t * 16;
#pragma unroll
  for (int i = 0; i < 16; ++i) { loc[i] = h[hi - i]; psum += loc[i]; }
  __shared__ uint32_t sc[BLK];
  sc[t] = psum;
  __syncthreads();
  for (int ofs = 1; ofs < BLK; ofs <<= 1) {
    uint32_t vv = (t >= ofs) ? sc[t - ofs] : 0u;
    __syncthreads();
    sc[t] += vv;
    __syncthreads();
  }
  uint32_t incl = sc[t];
  uint32_t total = sc[BLK - 1];
  int k = (int)((float)total * 0.66f);     // matches jnp f32 mul + trunc
  if (t == 0 && k == 0) { selhi[g] = -1; rem[g] = 0; }
  uint32_t excl = incl - psum;
  if (k > 0 && (int)excl < k && k <= (int)incl) {
    uint32_t cum = excl;
#pragma unroll
    for (int i = 0; i < 16; ++i) {
      if ((uint32_t)k <= cum + loc[i]) { selhi[g] = hi - i; rem[g] = k - (int)cum; break; }
      cum += loc[i];
    }
  }
}

// ---------------------------------------------------------------------------
// K4: refined 12-bit histogram (bits [19:8]) for pixels in the selected bin.
// ---------------------------------------------------------------------------
__global__ __launch_bounds__(BLK) void k_hist2(const float* __restrict__ mp,
                                               const uint8_t* __restrict__ lab,
                                               const int* __restrict__ selhi,
                                               uint32_t* __restrict__ hist2) {
  int p = blockIdx.x * BLK + threadIdx.x;
  int b = p >> 19;
  uint32_t u = __float_as_uint(mp[p]);
  int g = b * Ccls + (int)lab[p];
  int sh = selhi[g];
  if (sh >= 0 && (int)(u >> 20) == sh)
    atomicAdd(&hist2[g * BINS + (int)((u >> 8) & 0xFFFu)], 1u);
}

// ---------------------------------------------------------------------------
// K5: second scan -> 24-bit threshold. mask_topk = bits(mp) >= thresh.
// ---------------------------------------------------------------------------
__global__ __launch_bounds__(BLK) void k_select2(const uint32_t* __restrict__ hist2,
                                                 const int* __restrict__ selhi,
                                                 const int* __restrict__ rem,
                                                 uint32_t* __restrict__ thresh) {
  int g = blockIdx.x;
  int t = threadIdx.x;
  int sh = selhi[g];
  if (sh < 0) { if (t == 0) thresh[g] = 0x7F800000u; return; }  // k==0: select none
  const uint32_t* h = hist2 + g * BINS;
  uint32_t loc[16]; uint32_t psum = 0;
  int hi = BINS - 1 - t * 16;
#pragma unroll
  for (int i = 0; i < 16; ++i) { loc[i] = h[hi - i]; psum += loc[i]; }
  __shared__ uint32_t sc[BLK];
  sc[t] = psum;
  __syncthreads();
  for (int ofs = 1; ofs < BLK; ofs <<= 1) {
    uint32_t vv = (t >= ofs) ? sc[t - ofs] : 0u;
    __syncthreads();
    sc[t] += vv;
    __syncthreads();
  }
  uint32_t incl = sc[t];
  int k = rem[g];                       // 1 <= k <= hist1[g][sh]
  uint32_t excl = incl - psum;
  if (k > 0 && (int)excl < k && k <= (int)incl) {
    uint32_t cum = excl;
#pragma unroll
    for (int i = 0; i < 16; ++i) {
      if ((uint32_t)k <= cum + loc[i]) {
        thresh[g] = ((uint32_t)sh << 20) | ((uint32_t)(hi - i) << 8);
        break;
      }
      cum += loc[i];
    }
  }
}

// ---------------------------------------------------------------------------
// K6: masked reduction: sum(-log(mp)) and count over mask.
// ---------------------------------------------------------------------------
__global__ __launch_bounds__(BLK) void k_loss(const float* __restrict__ mp_arr,
                                              const uint8_t* __restrict__ lab,
                                              const uint32_t* __restrict__ thresh,
                                              float* __restrict__ gsum,
                                              uint32_t* __restrict__ gcnt) {
  int p = blockIdx.x * BLK + threadIdx.x;
  int b = p >> 19;
  float mp = mp_arr[p];
  int g = b * Ccls + (int)lab[p];
  uint32_t u = __float_as_uint(mp);
  bool sel = (mp > 0.9f) || (u >= thresh[g]);
  float vs = sel ? -logf(mp) : 0.f;
  uint32_t vc = sel ? 1u : 0u;
#pragma unroll
  for (int o = 32; o > 0; o >>= 1) {
    vs += __shfl_down(vs, o, 64);
    vc += __shfl_down(vc, o, 64);
  }
  __shared__ float ssum[BLK / 64];
  __shared__ uint32_t scnt[BLK / 64];
  int wave = threadIdx.x >> 6;
  int lane = threadIdx.x & 63;
  if (lane == 0) { ssum[wave] = vs; scnt[wave] = vc; }
  __syncthreads();
  if (threadIdx.x == 0) {
    float ts = 0.f; uint32_t tc = 0u;
#pragma unroll
    for (int w = 0; w < BLK / 64; ++w) { ts += ssum[w]; tc += scnt[w]; }
    atomicAdd(gsum, ts);
    atomicAdd(gcnt, tc);
  }
}

__global__ void k_final(const float* __restrict__ gsum,
                        const uint32_t* __restrict__ gcnt,
                        float* __restrict__ out) {
  uint32_t c = *gcnt;
  float d = (float)(c > 0u ? c : 1u);
  out[0] = *gsum / d;
}

// ---------------------------------------------------------------------------
extern "C" void kernel_launch(void* const* d_in, const int* in_sizes, int n_in,
                              void* d_out, int out_size, void* d_ws, size_t ws_size,
                              hipStream_t stream) {
  const float* pred = (const float*)d_in[0];
  char* ws = (char*)d_ws;
  size_t off = 0;
  auto carve = [&](size_t bytes) -> void* {
    void* p = ws + off;
    off = (off + bytes + 255) & ~(size_t)255;
    return p;
  };
  float*    mp    = (float*)carve((size_t)TotPix * 4);
  uint8_t*  lab   = (uint8_t*)carve((size_t)TotPix);
  size_t zero_off = off;
  uint32_t* hist1 = (uint32_t*)carve((size_t)NGroup * BINS * 4);
  uint32_t* hist2 = (uint32_t*)carve((size_t)NGroup * BINS * 4);
  int*      selhi = (int*)carve((size_t)NGroup * 4);
  int*      rem   = (int*)carve((size_t)NGroup * 4);
  uint32_t* thr   = (uint32_t*)carve((size_t)NGroup * 4);
  float*    gsum  = (float*)carve(4);
  uint32_t* gcnt  = (uint32_t*)carve(4);

  hipMemsetAsync(ws + zero_off, 0, off - zero_off, stream);

  int nblk = TotPix / BLK;
  k_pixel  <<<nblk,   BLK, 0, stream>>>(pred, mp, lab);
  k_hist1  <<<nblk,   BLK, 0, stream>>>(mp, lab, hist1);
  k_select1<<<NGroup, BLK, 0, stream>>>(hist1, selhi, rem);
  k_hist2  <<<nblk,   BLK, 0, stream>>>(mp, lab, selhi, hist2);
  k_select2<<<NGroup, BLK, 0, stream>>>(hist2, selhi, rem, thr);
  k_loss   <<<nblk,   BLK, 0, stream>>>(mp, lab, thr, gsum, gcnt);
  k_final  <<<1, 1, 0, stream>>>(gsum, gcnt, (float*)d_out);
}

// Round 2
// 496.490 us; speedup vs baseline: 2.1052x; 2.1052x over previous
//
#include <hip/hip_runtime.h>
#include <stdint.h>

#define BLK 256

constexpr int Bsz = 8, Ccls = 19, Hh = 512, Ww = 1024;
constexpr int Npix = Hh * Ww;          // 2^19
constexpr int TotPix = Bsz * Npix;     // 2^22
constexpr int NGroup = Bsz * Ccls;     // 152
constexpr int SUBS = 64;               // sub-histograms per image
constexpr int NB1 = 256;               // pass-1 bins (8-bit engineered key)
constexpr int NB2 = 4096;              // pass-2 bins (12 mantissa bits)
constexpr int KEY_BASE = 122 << 5;     // 3904: exponent 122 -> key 0

// key1 = (u>>18) - 3904 : monotone in u, in [0,192) for max_prob in [1/19, 1]
__device__ __forceinline__ int key1_of(uint32_t u) {
  int k = (int)(u >> 18) - KEY_BASE;
  return k < 0 ? 0 : (k > 255 ? 255 : k);
}

// ---------------------------------------------------------------------------
// K1 (fused): max/argmax + softmax denom + pass-1 LDS histogram.
// 512 blocks: block = b*64 + s handles pixels [s*8192, (s+1)*8192) of image b.
// Flush LDS hist (19x256 u32) non-atomically to h1[block][c][key].
// ---------------------------------------------------------------------------
__global__ __launch_bounds__(BLK) void k_fused(const float* __restrict__ pred,
                                               float4* __restrict__ mp_out,
                                               uchar4* __restrict__ lab_out,
                                               uint32_t* __restrict__ h1) {
  __shared__ uint32_t hist[Ccls * NB1];
  int t = threadIdx.x;
#pragma unroll
  for (int c = 0; c < Ccls; ++c) hist[c * NB1 + t] = 0;
  __syncthreads();

  int blk = blockIdx.x;
  int b = blk >> 6;
  int s = blk & 63;
  const float* ibase = pred + (size_t)b * Ccls * Npix;
  int n0 = s * 8192;

  for (int j = 0; j < 8; ++j) {
    int n = n0 + j * 1024 + t * 4;
    float4 v[Ccls];
#pragma unroll
    for (int c = 0; c < Ccls; ++c)
      v[c] = *(const float4*)(ibase + (size_t)c * Npix + n);

    float mp[4]; int lc[4];
#pragma unroll
    for (int q = 0; q < 4; ++q) {
      float m = ((const float*)&v[0])[q]; int l = 0;
#pragma unroll
      for (int c = 1; c < Ccls; ++c) {
        float x = ((const float*)&v[c])[q];
        if (x > m) { m = x; l = c; }
      }
      float sum = 0.f;
#pragma unroll
      for (int c = 0; c < Ccls; ++c) sum += __expf(((const float*)&v[c])[q] - m);
      mp[q] = 1.0f / sum;
      lc[q] = l;
      uint32_t u = __float_as_uint(mp[q]);
      atomicAdd(&hist[l * NB1 + key1_of(u)], 1u);
    }
    int p4 = b * (Npix / 4) + n / 4;
    mp_out[p4] = make_float4(mp[0], mp[1], mp[2], mp[3]);
    lab_out[p4] = make_uchar4((uint8_t)lc[0], (uint8_t)lc[1], (uint8_t)lc[2], (uint8_t)lc[3]);
  }

  __syncthreads();
  uint32_t* dst = h1 + (size_t)blk * (Ccls * NB1);
#pragma unroll
  for (int c = 0; c < Ccls; ++c) dst[c * NB1 + t] = hist[c * NB1 + t];
}

// ---------------------------------------------------------------------------
// K2: per-group select over 256 bins (thread t owns bin 255-t, descending).
// Sums 64 sub-histograms, scans, finds bin of k-th largest + residual rank.
// ---------------------------------------------------------------------------
__global__ __launch_bounds__(BLK) void k_select1(const uint32_t* __restrict__ h1,
                                                 int* __restrict__ selhi,
                                                 int* __restrict__ rem) {
  int g = blockIdx.x;
  int b = g / Ccls, c = g % Ccls;
  int t = threadIdx.x;
  int bin = NB1 - 1 - t;
  uint32_t cnt = 0;
  for (int s = 0; s < SUBS; ++s)
    cnt += h1[(size_t)(b * SUBS + s) * (Ccls * NB1) + c * NB1 + bin];
  __shared__ uint32_t sc[BLK];
  sc[t] = cnt;
  __syncthreads();
  for (int ofs = 1; ofs < BLK; ofs <<= 1) {
    uint32_t vv = (t >= ofs) ? sc[t - ofs] : 0u;
    __syncthreads();
    sc[t] += vv;
    __syncthreads();
  }
  uint32_t incl = sc[t];
  uint32_t excl = incl - cnt;
  uint32_t total = sc[BLK - 1];
  int k = (int)((float)total * 0.66f);   // matches jnp f32 mul + trunc
  if (t == 0 && k == 0) { selhi[g] = -1; rem[g] = 0; }
  if (k > 0 && (int)excl < k && k <= (int)incl) {
    selhi[g] = bin;
    rem[g] = k - (int)excl;
  }
}

// ---------------------------------------------------------------------------
// K3: refined histogram — pixels whose key1 matches the selected bin get
// binned by mantissa bits [17:6]. ~500/group -> negligible atomic contention.
// ---------------------------------------------------------------------------
__global__ __launch_bounds__(BLK) void k_hist2(const float4* __restrict__ mp,
                                               const uchar4* __restrict__ lab,
                                               const int* __restrict__ selhi,
                                               uint32_t* __restrict__ hist2) {
  int p4 = blockIdx.x * BLK + threadIdx.x;
  int b = p4 >> 17;                       // / (Npix/4)
  float4 m = mp[p4];
  uchar4 l = lab[p4];
  const float* mf = (const float*)&m;
  const uint8_t* lf = (const uint8_t*)&l;
#pragma unroll
  for (int q = 0; q < 4; ++q) {
    uint32_t u = __float_as_uint(mf[q]);
    int g = b * Ccls + (int)lf[q];
    if (key1_of(u) == selhi[g])
      atomicAdd(&hist2[g * NB2 + (int)((u >> 6) & 0xFFFu)], 1u);
  }
}

// ---------------------------------------------------------------------------
// K4: second select over 4096 bins (16 bins/thread, descending) -> threshold.
// thresh = bit-prefix such that mask_topk == (bits(mp) >= thresh).
// ---------------------------------------------------------------------------
__global__ __launch_bounds__(BLK) void k_select2(const uint32_t* __restrict__ hist2,
                                                 const int* __restrict__ selhi,
                                                 const int* __restrict__ rem,
                                                 uint32_t* __restrict__ thresh) {
  int g = blockIdx.x;
  int t = threadIdx.x;
  int sh = selhi[g];
  if (sh < 0) { if (t == 0) thresh[g] = 0x7F800000u; return; }
  const uint32_t* h = hist2 + g * NB2;
  uint32_t loc[16]; uint32_t psum = 0;
  int hi = NB2 - 1 - t * 16;
#pragma unroll
  for (int i = 0; i < 16; ++i) { loc[i] = h[hi - i]; psum += loc[i]; }
  __shared__ uint32_t sc[BLK];
  sc[t] = psum;
  __syncthreads();
  for (int ofs = 1; ofs < BLK; ofs <<= 1) {
    uint32_t vv = (t >= ofs) ? sc[t - ofs] : 0u;
    __syncthreads();
    sc[t] += vv;
    __syncthreads();
  }
  uint32_t incl = sc[t];
  int k = rem[g];
  uint32_t excl = incl - psum;
  if (k > 0 && (int)excl < k && k <= (int)incl) {
    uint32_t cum = excl;
#pragma unroll
    for (int i = 0; i < 16; ++i) {
      if ((uint32_t)k <= cum + loc[i]) {
        thresh[g] = ((uint32_t)(sh + KEY_BASE) << 18) | ((uint32_t)(hi - i) << 6);
        break;
      }
      cum += loc[i];
    }
  }
}

// ---------------------------------------------------------------------------
// K5: masked reduction: sum(-log(mp)) and count. nll(pseudo) == -log(max_prob).
// ---------------------------------------------------------------------------
__global__ __launch_bounds__(BLK) void k_loss(const float4* __restrict__ mp_arr,
                                              const uchar4* __restrict__ lab,
                                              const uint32_t* __restrict__ thresh,
                                              float* __restrict__ gsum,
                                              uint32_t* __restrict__ gcnt) {
  int p4 = blockIdx.x * BLK + threadIdx.x;
  int b = p4 >> 17;
  float4 m = mp_arr[p4];
  uchar4 l = lab[p4];
  const float* mf = (const float*)&m;
  const uint8_t* lf = (const uint8_t*)&l;
  float vs = 0.f; uint32_t vc = 0u;
#pragma unroll
  for (int q = 0; q < 4; ++q) {
    float mp = mf[q];
    int g = b * Ccls + (int)lf[q];
    uint32_t u = __float_as_uint(mp);
    bool sel = (mp > 0.9f) || (u >= thresh[g]);
    if (sel) { vs += -logf(mp); vc += 1u; }
  }
#pragma unroll
  for (int o = 32; o > 0; o >>= 1) {
    vs += __shfl_down(vs, o, 64);
    vc += __shfl_down(vc, o, 64);
  }
  __shared__ float ssum[BLK / 64];
  __shared__ uint32_t scnt[BLK / 64];
  int wave = threadIdx.x >> 6;
  int lane = threadIdx.x & 63;
  if (lane == 0) { ssum[wave] = vs; scnt[wave] = vc; }
  __syncthreads();
  if (threadIdx.x == 0) {
    float ts = 0.f; uint32_t tc = 0u;
#pragma unroll
    for (int w = 0; w < BLK / 64; ++w) { ts += ssum[w]; tc += scnt[w]; }
    atomicAdd(gsum, ts);
    atomicAdd(gcnt, tc);
  }
}

__global__ void k_final(const float* __restrict__ gsum,
                        const uint32_t* __restrict__ gcnt,
                        float* __restrict__ out) {
  uint32_t c = *gcnt;
  float d = (float)(c > 0u ? c : 1u);
  out[0] = *gsum / d;
}

// ---------------------------------------------------------------------------
extern "C" void kernel_launch(void* const* d_in, const int* in_sizes, int n_in,
                              void* d_out, int out_size, void* d_ws, size_t ws_size,
                              hipStream_t stream) {
  const float* pred = (const float*)d_in[0];
  char* ws = (char*)d_ws;
  size_t off = 0;
  auto carve = [&](size_t bytes) -> void* {
    void* p = ws + off;
    off = (off + bytes + 255) & ~(size_t)255;
    return p;
  };
  float*    mp    = (float*)carve((size_t)TotPix * 4);
  uint8_t*  lab   = (uint8_t*)carve((size_t)TotPix);
  uint32_t* h1    = (uint32_t*)carve((size_t)Bsz * SUBS * Ccls * NB1 * 4);  // written fully, no memset
  int*      selhi = (int*)carve((size_t)NGroup * 4);
  int*      rem   = (int*)carve((size_t)NGroup * 4);
  uint32_t* thr   = (uint32_t*)carve((size_t)NGroup * 4);
  size_t zero_off = off;                 // memset region: hist2 + gsum + gcnt
  uint32_t* hist2 = (uint32_t*)carve((size_t)NGroup * NB2 * 4);
  float*    gsum  = (float*)carve(4);
  uint32_t* gcnt  = (uint32_t*)carve(4);

  hipMemsetAsync(ws + zero_off, 0, off - zero_off, stream);

  int nblk4 = TotPix / (BLK * 4);        // 4096
  k_fused  <<<Bsz * SUBS, BLK, 0, stream>>>(pred, (float4*)mp, (uchar4*)lab, h1);
  k_select1<<<NGroup,     BLK, 0, stream>>>(h1, selhi, rem);
  k_hist2  <<<nblk4,      BLK, 0, stream>>>((const float4*)mp, (const uchar4*)lab, selhi, hist2);
  k_select2<<<NGroup,     BLK, 0, stream>>>(hist2, selhi, rem, thr);
  k_loss   <<<nblk4,      BLK, 0, stream>>>((const float4*)mp, (const uchar4*)lab, thr, gsum, gcnt);
  k_final  <<<1, 1, 0, stream>>>(gsum, gcnt, (float*)d_out);
}